// Round 2
// baseline (232.769 us; speedup 1.0000x reference)
//
#include <hip/hip_runtime.h>
#include <hip/hip_bf16.h>

#define NFFT   4194304
#define NMODES 2
#define NTAPS  101
#define NVALID (NFFT - NTAPS + 1)   // 4194204
#define N0     (NTAPS / 2)          // 50

constexpr int BLOCK = 256;                          // 4 waves
constexpr int TILE  = 2048;                         // output samples per block (512/wave)
constexpr int NT    = (NVALID + TILE - 1) / TILE;   // 2048 blocks, one tile each
constexpr int WIN   = 2176;                         // staged P samples (max read idx 2151)
constexpr int NM    = 15;                           // banded MFMA accumulation steps

typedef __attribute__((ext_vector_type(8)))  short short8;
typedef __attribute__((ext_vector_type(16))) float float16;

static __device__ __forceinline__ unsigned short f2bf(float x) {
    __hip_bfloat16 h = __float2bfloat16(x);
    return *reinterpret_cast<unsigned short*>(&h);
}
static __device__ __forceinline__ unsigned pk(float e0, float e1) {
    return (unsigned)f2bf(e0) | ((unsigned)f2bf(e1) << 16);
}
// XOR word bits 2..4 with sample bits 5..7: keeps 16B alignment of 4-word groups,
// spreads the 64B-stride fragment reads across banks (residual 2-way = free).
static __device__ __forceinline__ int swz(int s) {
    return s ^ (((s >> 5) & 7) << 2);
}

__global__ __launch_bounds__(BLOCK, 4) void nl_kernel(
    const float* __restrict__ xa,   // d_in[0] big stream (A = xr)
    const float* __restrict__ xb,   // d_in[1] big stream (B = xi)
    const float* __restrict__ W,  const float* __restrict__ b,
    const float* __restrict__ power, unsigned* __restrict__ out)
{
    // Phase 1: Pl[swz(s)] = bf16x2 P sample s (mode0 low, mode1 high), 2176 words.
    // Phase 2 (aliased, after barrier): Ph[swz(w)] = phi, w = 2*local_sample + mode, 4096 words.
    __shared__ __align__(16) unsigned lds[2 * TILE];          // 16 KB
    unsigned* __restrict__ Pl = lds;
    float*    __restrict__ Ph = reinterpret_cast<float*>(lds);

    const int tid  = threadIdx.x;
    const int lane = tid & 63;
    const int wid  = tid >> 6;
    const int colc = lane & 31;      // B/C column = (c_s<<1)|o ; also A row index
    const int h    = lane >> 5;      // k half: k = 8h + e
    const int cs   = colc >> 1;      // fine shift 0..15
    const int o    = colc & 1;       // output mode
    const int r    = colc;           // A row

    const int tile_start = blockIdx.x * TILE;

    // ---- B fragments: B_m[k=(dt,i)][c=(cs,o)] = W[8m + dt - cs, i, o], banded ----
    short8 Bf[NM];
    const float4* __restrict__ Wt = reinterpret_cast<const float4*>(W); // W[t]={i0o0,i0o1,i1o0,i1o1}
    #pragma unroll
    for (int m = 0; m < NM; ++m) {
        short8 bb;
        #pragma unroll
        for (int d = 0; d < 4; ++d) {
            const int t  = 8 * m + 4 * h + d - cs;
            const bool ok = (unsigned)t <= 100u;
            const float4 w = Wt[ok ? t : 0];
            bb[2 * d]     = (short)f2bf(ok ? (o ? w.y : w.x) : 0.f);  // i=0
            bb[2 * d + 1] = (short)f2bf(ok ? (o ? w.w : w.z) : 0.f);  // i=1
        }
        Bf[m] = bb;
    }

    // ---- stage P = xa^2 + xb^2 as bf16x2 into swizzled LDS (inline, R0 pattern) ----
    const float4* __restrict__ xa4 = reinterpret_cast<const float4*>(xa); // 2 samples
    const float4* __restrict__ xb4 = reinterpret_cast<const float4*>(xb);
    #pragma unroll
    for (int k = 0; k < 5; ++k) {
        const int s = 2 * tid + 512 * k;            // even
        if (k < 4 || s < WIN) {
            const int g = tile_start + s;
            float4 a = make_float4(0.f, 0.f, 0.f, 0.f), c = a;
            if (g < NFFT) { a = xa4[g >> 1]; c = xb4[g >> 1]; }
            const unsigned u0 = pk(a.x * a.x + c.x * c.x, a.y * a.y + c.y * c.y);
            const unsigned u1 = pk(a.z * a.z + c.z * c.z, a.w * a.w + c.w * c.w);
            *reinterpret_cast<uint2*>(&Pl[swz(s)]) = make_uint2(u0, u1);
        }
    }
    __syncthreads();

    // ---- per-wave 512-sample chunk: 15 x (aligned ds_read_b128 + 32x32x16 MFMA) ----
    // A_m[r][k=(dt,i)] = P[cb + 16r + 8m + dt, i]; lane (r,h) reads one aligned uint4.
    const int cb = wid * 512;
    float16 acc = {};
    uint4 areg[4];                    // 4-deep A prefetch pipe (static idx post-unroll)
    #pragma unroll
    for (int m = 0; m < 4; ++m)
        areg[m] = *reinterpret_cast<const uint4*>(&Pl[swz(cb + 16 * r + 8 * m + 4 * h)]);
    #pragma unroll
    for (int m = 0; m < NM; ++m) {
        acc = __builtin_amdgcn_mfma_f32_32x32x16_bf16(
                  __builtin_bit_cast(short8, areg[m & 3]), Bf[m], acc, 0, 0, 0);
        if (m + 4 < NM)
            areg[m & 3] = *reinterpret_cast<const uint4*>(
                              &Pl[swz(cb + 16 * r + 8 * (m + 4) + 4 * h)]);
    }

    // ---- phase A: scatter phi(+bias) into LDS per C/D layout ----
    // C/D: col = lane&31, row = (reg&3) + 8*(reg>>2) + 4*(lane>>5)
    // local sample = cb + 16*row + cs, word w = 2*local + o = wid*1024 + 32*row + colc.
    const float bo = o ? b[1] : b[0];
    __syncthreads();                  // all waves done reading Pl before aliasing write
    #pragma unroll
    for (int j = 0; j < 16; ++j) {
        const int row = (j & 3) + 8 * (j >> 2) + 4 * h;
        const int w   = wid * 1024 + 32 * row + colc;   // contiguous per half-wave
        Ph[swz(w)] = acc[j] + bo;
    }
    __syncthreads();

    // ---- phase B: R0-verified epilogue, 8 consecutive samples per thread ----
    const float coef = 0.066268f * exp10f(power[0] * 0.1f);
    float phiv[16];                   // phi for samples 8*tid .. 8*tid+7, both modes
    #pragma unroll
    for (int q = 0; q < 4; ++q) {
        const int w = 16 * tid + 4 * q;               // 16B-aligned group, swz-compatible
        *reinterpret_cast<float4*>(&phiv[4 * q]) =
            *reinterpret_cast<const float4*>(&Ph[swz(w)]);
    }

    const int base = tile_start + tid * 8;
    const float2* __restrict__ xa2 = reinterpret_cast<const float2*>(xa);
    const float2* __restrict__ xb2 = reinterpret_cast<const float2*>(xb);
    uint4* __restrict__ out4 = reinterpret_cast<uint4*>(out);

    #pragma unroll
    for (int cc = 0; cc < 4; ++cc) {
        const int n0v = base + 2 * cc;                // even
        if (n0v + 1 < NVALID) {                       // fast path: both samples valid
            const float4 A = xa4[(n0v + N0) >> 1];    // {s0.m0, s0.m1, s1.m0, s1.m1}
            const float4 B = xb4[(n0v + N0) >> 1];
            float s00, c00, s01, c01, s10, c10, s11, c11;
            __sincosf(phiv[4 * cc + 0] * coef, &s00, &c00);
            __sincosf(phiv[4 * cc + 1] * coef, &s01, &c01);
            __sincosf(phiv[4 * cc + 2] * coef, &s10, &c10);
            __sincosf(phiv[4 * cc + 3] * coef, &s11, &c11);
            uint4 ov;
            ov.x = pk(B.x * c00 - A.x * s00, A.x * c00 + B.x * s00); // s0 mode0
            ov.y = pk(B.y * c01 - A.y * s01, A.y * c01 + B.y * s01); // s0 mode1
            ov.z = pk(B.z * c10 - A.z * s10, A.z * c10 + B.z * s10); // s1 mode0
            ov.w = pk(B.w * c11 - A.w * s11, A.w * c11 + B.w * s11); // s1 mode1
            out4[n0v >> 1] = ov;
        } else {
            #pragma unroll
            for (int dc = 0; dc < 2; ++dc) {
                const int n = n0v + dc;
                if (n < NVALID) {
                    const float2 A = xa2[n + N0];
                    const float2 B = xb2[n + N0];
                    float s0, c0s, s1, c1s;
                    __sincosf(phiv[4 * cc + 2 * dc + 0] * coef, &s0, &c0s);
                    __sincosf(phiv[4 * cc + 2 * dc + 1] * coef, &s1, &c1s);
                    uint2 ov;
                    ov.x = pk(B.x * c0s - A.x * s0, A.x * c0s + B.x * s0);
                    ov.y = pk(B.y * c1s - A.y * s1, A.y * c1s + B.y * s1);
                    reinterpret_cast<uint2*>(out)[n] = ov;
                }
            }
        }
    }
}

extern "C" void kernel_launch(void* const* d_in, const int* in_sizes, int n_in,
                              void* d_out, int out_size, void* d_ws, size_t ws_size,
                              hipStream_t stream) {
    // Bind by size (robust): big arrays = x streams, 404 = W, 2 = b, 1 = power.
    const float* big[2] = {nullptr, nullptr};
    const float* W = nullptr; const float* b = nullptr; const float* power = nullptr;
    int nbig = 0;
    for (int i = 0; i < n_in; ++i) {
        const float* p = (const float*)d_in[i];
        const int sz = in_sizes[i];
        if (sz == NFFT * NMODES)       { if (nbig < 2) big[nbig++] = p; }
        else if (sz == NTAPS * NMODES * NMODES) { W = p; }
        else if (sz == NMODES)         { b = p; }
        else if (sz == 1)              { power = p; }
    }

    unsigned* out = (unsigned*)d_out;
    nl_kernel<<<NT, BLOCK, 0, stream>>>(big[0], big[1], W, b, power, out);
}

// Round 3
// 141.644 us; speedup vs baseline: 1.6433x; 1.6433x over previous
//
#include <hip/hip_runtime.h>
#include <hip/hip_bf16.h>

#define NFFT   4194304
#define NMODES 2
#define NTAPS  101
#define NVALID (NFFT - NTAPS + 1)   // 4194204
#define N0     (NTAPS / 2)          // 50

constexpr int BLOCK = 256;                          // 4 waves
constexpr int TILE  = 2048;                         // output samples per block (512/wave)
constexpr int NT    = (NVALID + TILE - 1) / TILE;   // 2048 blocks, one tile each
constexpr int WIN   = 2176;                         // staged P samples (max read idx 2151)
constexpr int NM    = 15;                           // banded MFMA accumulation steps

typedef __attribute__((ext_vector_type(8)))  short short8;
typedef __attribute__((ext_vector_type(16))) float float16;

static __device__ __forceinline__ unsigned short f2bf(float x) {
    __hip_bfloat16 h = __float2bfloat16(x);
    return *reinterpret_cast<unsigned short*>(&h);
}
static __device__ __forceinline__ unsigned pk(float e0, float e1) {
    return (unsigned)f2bf(e0) | ((unsigned)f2bf(e1) << 16);
}
// XOR word bits 2..4 with sample bits 5..7: keeps 16B alignment of 4-word groups,
// spreads the 64B-stride fragment reads across banks (residual 2-way = free).
static __device__ __forceinline__ int swz(int s) {
    return s ^ (((s >> 5) & 7) << 2);
}

__global__ __launch_bounds__(BLOCK, 4) void nl_kernel(
    const float* __restrict__ xa,   // d_in[0] big stream (A = xr)
    const float* __restrict__ xb,   // d_in[1] big stream (B = xi)
    const float* __restrict__ W,  const float* __restrict__ b,
    const float* __restrict__ power, unsigned* __restrict__ out)
{
    // Phase 1: Pl[swz(s)] = bf16x2 P sample s (mode0 low, mode1 high), 2176 words.
    // Phase 2 (aliased, after barrier): Ph[swz(w)] = phi, w = 2*local_sample + mode.
    __shared__ __align__(16) unsigned lds[2 * TILE];     // 16 KB
    // Per-lane B fragments, built cooperatively: Btab[m*256 + lane*4 + d].
    __shared__ __align__(16) unsigned Btab[NM * 256];    // 15 KB
    unsigned* __restrict__ Pl = lds;
    float*    __restrict__ Ph = reinterpret_cast<float*>(lds);

    const int tid  = threadIdx.x;
    const int lane = tid & 63;
    const int wid  = tid >> 6;
    const int colc = lane & 31;      // B/C column = (c_s<<1)|o ; also A row index
    const int h    = lane >> 5;      // k half: k = 8h + e
    const int cs   = colc >> 1;      // fine shift 0..15
    const int o    = colc & 1;       // output mode
    const int r    = colc;           // A row

    const int tile_start = blockIdx.x * TILE;

    // ---- stage P = xa^2 + xb^2 as bf16x2 into swizzled LDS ----
    const float4* __restrict__ xa4 = reinterpret_cast<const float4*>(xa); // 2 samples
    const float4* __restrict__ xb4 = reinterpret_cast<const float4*>(xb);
    #pragma unroll
    for (int k = 0; k < 5; ++k) {
        const int s = 2 * tid + 512 * k;            // even
        if (k < 4 || s < WIN) {
            const int g = tile_start + s;
            float4 a = make_float4(0.f, 0.f, 0.f, 0.f), c = a;
            if (g < NFFT) { a = xa4[g >> 1]; c = xb4[g >> 1]; }
            const unsigned u0 = pk(a.x * a.x + c.x * c.x, a.y * a.y + c.y * c.y);
            const unsigned u1 = pk(a.z * a.z + c.z * c.z, a.w * a.w + c.w * c.w);
            *reinterpret_cast<uint2*>(&Pl[swz(s)]) = make_uint2(u0, u1);
        }
    }

    // Keep the staging load cluster and the W-load cluster apart (spill control).
    __builtin_amdgcn_sched_barrier(0);

    // ---- build B table cooperatively: one word per thread per m ----
    // Word (m, l, d): t = 8m + 4h(l) + d - cs(l); value = pk(W[t,0,o(l)], W[t,1,o(l)])
    {
        const float4* __restrict__ Wt = reinterpret_cast<const float4*>(W);
        const int l  = tid >> 2, d = tid & 3;
        const int lc = (l & 31) >> 1;    // cs of lane l
        const int lo = l & 1;            // o  of lane l
        const int lh = l >> 5;           // h  of lane l
        #pragma unroll 3
        for (int m = 0; m < NM; ++m) {
            const int t  = 8 * m + 4 * lh + d - lc;
            const bool ok = (unsigned)t <= 100u;
            const float4 w = Wt[ok ? t : 0];
            Btab[m * 256 + tid] = ok ? pk(lo ? w.y : w.x, lo ? w.w : w.z) : 0u;
        }
    }
    __builtin_amdgcn_sched_barrier(0);
    __syncthreads();

    // ---- per-wave 512-sample chunk: 15 x (2 ds_read_b128 + 32x32x16 MFMA) ----
    // A_m[r][k=(dt,i)] = P[cb + 16r + 8m + dt, i]; lane (r,h) reads one aligned uint4.
    const int cb = wid * 512;
    float16 acc = {};
    uint4 areg[4];                    // 4-deep A prefetch pipe (static idx post-unroll)
    #pragma unroll
    for (int m = 0; m < 4; ++m)
        areg[m] = *reinterpret_cast<const uint4*>(&Pl[swz(cb + 16 * r + 8 * m + 4 * h)]);
    #pragma unroll
    for (int m = 0; m < NM; ++m) {
        const uint4 bq = *reinterpret_cast<const uint4*>(&Btab[m * 256 + (lane << 2)]);
        acc = __builtin_amdgcn_mfma_f32_32x32x16_bf16(
                  __builtin_bit_cast(short8, areg[m & 3]),
                  __builtin_bit_cast(short8, bq), acc, 0, 0, 0);
        if (m + 4 < NM)
            areg[m & 3] = *reinterpret_cast<const uint4*>(
                              &Pl[swz(cb + 16 * r + 8 * (m + 4) + 4 * h)]);
    }

    // ---- phase A: scatter phi(+bias) into LDS per C/D layout ----
    // C/D: col = lane&31, row = (reg&3) + 8*(reg>>2) + 4*(lane>>5)
    // word w = 2*local_sample + o = wid*1024 + 32*row + colc (contiguous per half-wave).
    const float bo = o ? b[1] : b[0];
    __syncthreads();                  // all waves done reading Pl before aliasing write
    #pragma unroll
    for (int j = 0; j < 16; ++j) {
        const int row = (j & 3) + 8 * (j >> 2) + 4 * h;
        const int w   = wid * 1024 + 32 * row + colc;
        Ph[swz(w)] = acc[j] + bo;
    }
    __syncthreads();

    // ---- phase B: R0-verified epilogue, 8 consecutive samples per thread ----
    const float coef = 0.066268f * exp10f(power[0] * 0.1f);
    float phiv[16];                   // phi for samples 8*tid .. 8*tid+7, both modes
    #pragma unroll
    for (int q = 0; q < 4; ++q) {
        const int w = 16 * tid + 4 * q;               // 16B-aligned group, swz-compatible
        *reinterpret_cast<float4*>(&phiv[4 * q]) =
            *reinterpret_cast<const float4*>(&Ph[swz(w)]);
    }

    const int base = tile_start + tid * 8;
    const float2* __restrict__ xa2 = reinterpret_cast<const float2*>(xa);
    const float2* __restrict__ xb2 = reinterpret_cast<const float2*>(xb);
    uint4* __restrict__ out4 = reinterpret_cast<uint4*>(out);

    #pragma unroll
    for (int cc = 0; cc < 4; ++cc) {
        const int n0v = base + 2 * cc;                // even
        if (n0v + 1 < NVALID) {                       // fast path: both samples valid
            const float4 A = xa4[(n0v + N0) >> 1];    // {s0.m0, s0.m1, s1.m0, s1.m1}
            const float4 B = xb4[(n0v + N0) >> 1];
            float s00, c00, s01, c01, s10, c10, s11, c11;
            __sincosf(phiv[4 * cc + 0] * coef, &s00, &c00);
            __sincosf(phiv[4 * cc + 1] * coef, &s01, &c01);
            __sincosf(phiv[4 * cc + 2] * coef, &s10, &c10);
            __sincosf(phiv[4 * cc + 3] * coef, &s11, &c11);
            uint4 ov;
            ov.x = pk(B.x * c00 - A.x * s00, A.x * c00 + B.x * s00); // s0 mode0
            ov.y = pk(B.y * c01 - A.y * s01, A.y * c01 + B.y * s01); // s0 mode1
            ov.z = pk(B.z * c10 - A.z * s10, A.z * c10 + B.z * s10); // s1 mode0
            ov.w = pk(B.w * c11 - A.w * s11, A.w * c11 + B.w * s11); // s1 mode1
            out4[n0v >> 1] = ov;
        } else {
            #pragma unroll
            for (int dc = 0; dc < 2; ++dc) {
                const int n = n0v + dc;
                if (n < NVALID) {
                    const float2 A = xa2[n + N0];
                    const float2 B = xb2[n + N0];
                    float s0, c0s, s1, c1s;
                    __sincosf(phiv[4 * cc + 2 * dc + 0] * coef, &s0, &c0s);
                    __sincosf(phiv[4 * cc + 2 * dc + 1] * coef, &s1, &c1s);
                    uint2 ov;
                    ov.x = pk(B.x * c0s - A.x * s0, A.x * c0s + B.x * s0);
                    ov.y = pk(B.y * c1s - A.y * s1, A.y * c1s + B.y * s1);
                    reinterpret_cast<uint2*>(out)[n] = ov;
                }
            }
        }
    }
}

extern "C" void kernel_launch(void* const* d_in, const int* in_sizes, int n_in,
                              void* d_out, int out_size, void* d_ws, size_t ws_size,
                              hipStream_t stream) {
    // Bind by size (robust): big arrays = x streams, 404 = W, 2 = b, 1 = power.
    const float* big[2] = {nullptr, nullptr};
    const float* W = nullptr; const float* b = nullptr; const float* power = nullptr;
    int nbig = 0;
    for (int i = 0; i < n_in; ++i) {
        const float* p = (const float*)d_in[i];
        const int sz = in_sizes[i];
        if (sz == NFFT * NMODES)       { if (nbig < 2) big[nbig++] = p; }
        else if (sz == NTAPS * NMODES * NMODES) { W = p; }
        else if (sz == NMODES)         { b = p; }
        else if (sz == 1)              { power = p; }
    }

    unsigned* out = (unsigned*)d_out;
    nl_kernel<<<NT, BLOCK, 0, stream>>>(big[0], big[1], W, b, power, out);
}

// Round 4
// 127.894 us; speedup vs baseline: 1.8200x; 1.1075x over previous
//
#include <hip/hip_runtime.h>
#include <hip/hip_bf16.h>

#define NFFT   4194304
#define NMODES 2
#define NTAPS  101
#define NVALID (NFFT - NTAPS + 1)   // 4194204
#define N0     (NTAPS / 2)          // 50

constexpr int BLOCK = 256;                          // 4 waves
constexpr int TILE  = 2048;                         // output samples per block (512/wave)
constexpr int NT    = (NVALID + TILE - 1) / TILE;   // 2048 blocks, one tile each
constexpr int WIN   = 2176;                         // staged P samples (max read idx 2151)
constexpr int NM    = 15;                           // banded MFMA accumulation steps

typedef __attribute__((ext_vector_type(8)))  short short8;
typedef __attribute__((ext_vector_type(16))) float float16;

static __device__ __forceinline__ unsigned short f2bf(float x) {
    __hip_bfloat16 h = __float2bfloat16(x);
    return *reinterpret_cast<unsigned short*>(&h);
}
static __device__ __forceinline__ unsigned pk(float e0, float e1) {
    return (unsigned)f2bf(e0) | ((unsigned)f2bf(e1) << 16);
}
// XOR word bits 2..4 with sample bits 5..7: keeps 16B alignment of 4-word groups,
// spreads the 64B-stride fragment reads across banks (residual 2-way = free).
static __device__ __forceinline__ int swz(int s) {
    return s ^ (((s >> 5) & 7) << 2);
}

__global__ __launch_bounds__(BLOCK, 5) void nl_kernel(
    const float* __restrict__ xa,   // d_in[0] big stream (A = xr)
    const float* __restrict__ xb,   // d_in[1] big stream (B = xi)
    const float* __restrict__ W,  const float* __restrict__ b,
    const float* __restrict__ power, unsigned* __restrict__ out)
{
    // Pl[swz(s)] = bf16x2 P sample s (mode0 low, mode1 high), 2176 words = 8.5 KB.
    __shared__ __align__(16) unsigned Pl[WIN];
    // Per-lane B fragments, built cooperatively: Btab[m*256 + lane*4 + d] = 15 KB.
    __shared__ __align__(16) unsigned Btab[NM * 256];

    const int tid  = threadIdx.x;
    const int lane = tid & 63;
    const int wid  = tid >> 6;
    const int colc = lane & 31;      // B/C column = (c_s<<1)|o ; also A row index
    const int h    = lane >> 5;      // k half: k = 8h + e
    const int cs   = colc >> 1;      // fine shift 0..15
    const int o    = colc & 1;       // output mode
    const int r    = colc;           // A row

    const int tile_start = blockIdx.x * TILE;

    // ---- stage P = xa^2 + xb^2 as bf16x2 into swizzled LDS ----
    const float4* __restrict__ xa4 = reinterpret_cast<const float4*>(xa); // 2 samples
    const float4* __restrict__ xb4 = reinterpret_cast<const float4*>(xb);
    #pragma unroll
    for (int k = 0; k < 5; ++k) {
        const int s = 2 * tid + 512 * k;            // even
        if (k < 4 || s < WIN) {
            const int g = tile_start + s;
            float4 a = make_float4(0.f, 0.f, 0.f, 0.f), c = a;
            if (g < NFFT) { a = xa4[g >> 1]; c = xb4[g >> 1]; }
            const unsigned u0 = pk(a.x * a.x + c.x * c.x, a.y * a.y + c.y * c.y);
            const unsigned u1 = pk(a.z * a.z + c.z * c.z, a.w * a.w + c.w * c.w);
            *reinterpret_cast<uint2*>(&Pl[swz(s)]) = make_uint2(u0, u1);
        }
    }

    // Keep the staging load cluster and the W-load cluster apart (spill control).
    __builtin_amdgcn_sched_barrier(0);

    // ---- build B table cooperatively: one word per thread per m ----
    // Word (m, l, d): t = 8m + 4h(l) + d - cs(l); value = pk(W[t,0,o(l)], W[t,1,o(l)])
    {
        const float4* __restrict__ Wt = reinterpret_cast<const float4*>(W);
        const int l  = tid >> 2, d = tid & 3;
        const int lc = (l & 31) >> 1;    // cs of lane l
        const int lo = l & 1;            // o  of lane l
        const int lh = l >> 5;           // h  of lane l
        #pragma unroll 3
        for (int m = 0; m < NM; ++m) {
            const int t  = 8 * m + 4 * lh + d - lc;
            const bool ok = (unsigned)t <= 100u;
            const float4 w = Wt[ok ? t : 0];
            Btab[m * 256 + tid] = ok ? pk(lo ? w.y : w.x, lo ? w.w : w.z) : 0u;
        }
    }
    __builtin_amdgcn_sched_barrier(0);
    __syncthreads();

    // ---- per-wave 512-sample chunk: 15 x (2 ds_read_b128 + 32x32x16 MFMA) ----
    // A_m[r][k=(dt,i)] = P[cb + 16r + 8m + dt, i]; lane (r,h) reads one aligned uint4.
    const int cb = wid * 512;
    float16 acc = {};
    uint4 areg[4];                    // 4-deep A prefetch pipe (static idx post-unroll)
    #pragma unroll
    for (int m = 0; m < 4; ++m)
        areg[m] = *reinterpret_cast<const uint4*>(&Pl[swz(cb + 16 * r + 8 * m + 4 * h)]);
    #pragma unroll
    for (int m = 0; m < NM; ++m) {
        const uint4 bq = *reinterpret_cast<const uint4*>(&Btab[m * 256 + (lane << 2)]);
        acc = __builtin_amdgcn_mfma_f32_32x32x16_bf16(
                  __builtin_bit_cast(short8, areg[m & 3]),
                  __builtin_bit_cast(short8, bq), acc, 0, 0, 0);
        if (m + 4 < NM)
            areg[m & 3] = *reinterpret_cast<const uint4*>(
                              &Pl[swz(cb + 16 * r + 8 * (m + 4) + 4 * h)]);
    }

    // ---- epilogue: straight from accumulators, no LDS round-trip ----
    // C/D: col = lane&31, row = (reg&3) + 8*(reg>>2) + 4*(lane>>5);
    // out-word index = (n*2+o) = base*2 + 32*row + colc -> per j the wave touches
    // two full 128B segments (h=0 rows r, h=1 rows r+4): fully coalesced dwords.
    const float bo   = o ? b[1] : b[0];
    const float coef = 0.066268f * exp10f(power[0] * 0.1f);
    #pragma unroll
    for (int j = 0; j < 16; ++j) {
        const int row = (j & 3) + 8 * (j >> 2) + 4 * h;
        const int n   = tile_start + cb + 16 * row + cs;
        if (n < NVALID) {
            const float Ax = xa[(n + N0) * 2 + o];
            const float Bx = xb[(n + N0) * 2 + o];
            float sn, cn;
            __sincosf((acc[j] + bo) * coef, &sn, &cn);
            const unsigned ov = pk(Bx * cn - Ax * sn, Ax * cn + Bx * sn);
            __builtin_nontemporal_store(ov, &out[n * 2 + o]);   // out never re-read
        }
    }
}

extern "C" void kernel_launch(void* const* d_in, const int* in_sizes, int n_in,
                              void* d_out, int out_size, void* d_ws, size_t ws_size,
                              hipStream_t stream) {
    // Bind by size (robust): big arrays = x streams, 404 = W, 2 = b, 1 = power.
    const float* big[2] = {nullptr, nullptr};
    const float* W = nullptr; const float* b = nullptr; const float* power = nullptr;
    int nbig = 0;
    for (int i = 0; i < n_in; ++i) {
        const float* p = (const float*)d_in[i];
        const int sz = in_sizes[i];
        if (sz == NFFT * NMODES)       { if (nbig < 2) big[nbig++] = p; }
        else if (sz == NTAPS * NMODES * NMODES) { W = p; }
        else if (sz == NMODES)         { b = p; }
        else if (sz == 1)              { power = p; }
    }

    unsigned* out = (unsigned*)d_out;
    nl_kernel<<<NT, BLOCK, 0, stream>>>(big[0], big[1], W, b, power, out);
}

// Round 5
// 121.888 us; speedup vs baseline: 1.9097x; 1.0493x over previous
//
#include <hip/hip_runtime.h>
#include <hip/hip_bf16.h>

#define NFFT   4194304
#define NMODES 2
#define NTAPS  101
#define NVALID (NFFT - NTAPS + 1)   // 4194204
#define N0     (NTAPS / 2)          // 50

constexpr int BLOCK = 256;                          // 4 waves
constexpr int TILE  = 2048;                         // output samples per block (512/wave)
constexpr int NT    = (NVALID + TILE - 1) / TILE;   // 2048 blocks, one tile each
constexpr int WIN   = 2176;                         // staged P samples (max read idx 2151)
constexpr int NM    = 15;                           // banded MFMA accumulation steps
constexpr int TBW   = 272;                          // B-table words: t in [-15,119] x o, padded

typedef __attribute__((ext_vector_type(8)))  short short8;
typedef __attribute__((ext_vector_type(16))) float float16;

static __device__ __forceinline__ unsigned short f2bf(float x) {
    __hip_bfloat16 h = __float2bfloat16(x);
    return *reinterpret_cast<unsigned short*>(&h);
}
static __device__ __forceinline__ unsigned pk(float e0, float e1) {
    return (unsigned)f2bf(e0) | ((unsigned)f2bf(e1) << 16);
}
// XOR word bits 2..4 with sample bits 5..7: keeps 16B alignment of 4-word groups,
// spreads the 64B-stride fragment reads across banks (residual 2-way = free).
static __device__ __forceinline__ int swz(int s) {
    return s ^ (((s >> 5) & 7) << 2);
}

__global__ __launch_bounds__(BLOCK, 8) void nl_kernel(
    const float* __restrict__ xa,   // d_in[0] big stream (A = xr)
    const float* __restrict__ xb,   // d_in[1] big stream (B = xi)
    const float* __restrict__ W,  const float* __restrict__ b,
    const float* __restrict__ power, unsigned* __restrict__ out)
{
    // Pl[swz(s)] = bf16x2 P sample s (mode0 low, mode1 high), 2176 words = 8.5 KB.
    __shared__ __align__(16) unsigned Pl[WIN];
    // Compact B table: Bt[(t+15)*2 + o] = pk(W[t,0,o], W[t,1,o]), zero outside [0,100].
    __shared__ __align__(16) unsigned Bt[TBW];       // ~1.1 KB

    const int tid  = threadIdx.x;
    const int lane = tid & 63;
    const int wid  = tid >> 6;
    const int colc = lane & 31;      // B/C column = (c_s<<1)|o ; also A row index
    const int h    = lane >> 5;      // k half: k = 8h + e
    const int cs   = colc >> 1;      // fine shift 0..15
    const int o    = colc & 1;       // output mode
    const int r    = colc;           // A row

    const int tile_start = blockIdx.x * TILE;

    // ---- stage P = xa^2 + xb^2 as bf16x2 into swizzled LDS ----
    const float4* __restrict__ xa4 = reinterpret_cast<const float4*>(xa); // 2 samples
    const float4* __restrict__ xb4 = reinterpret_cast<const float4*>(xb);
    #pragma unroll
    for (int k = 0; k < 5; ++k) {
        const int s = 2 * tid + 512 * k;            // even
        if (k < 4 || s < WIN) {
            const int g = tile_start + s;
            float4 a = make_float4(0.f, 0.f, 0.f, 0.f), c = a;
            if (g < NFFT) { a = xa4[g >> 1]; c = xb4[g >> 1]; }
            const unsigned u0 = pk(a.x * a.x + c.x * c.x, a.y * a.y + c.y * c.y);
            const unsigned u1 = pk(a.z * a.z + c.z * c.z, a.w * a.w + c.w * c.w);
            *reinterpret_cast<uint2*>(&Pl[swz(s)]) = make_uint2(u0, u1);
        }
    }

    __builtin_amdgcn_sched_barrier(0);

    // ---- build compact B table: one word per (t,o), 270 live words ----
    {
        const float4* __restrict__ Wt = reinterpret_cast<const float4*>(W);
        #pragma unroll
        for (int idx = tid; idx < TBW; idx += BLOCK) {
            const int t  = (idx >> 1) - 15;
            const int oo = idx & 1;
            const bool ok = (unsigned)t <= 100u;
            const float4 w = Wt[ok ? t : 0];
            Bt[idx] = ok ? pk(oo ? w.y : w.x, oo ? w.w : w.z) : 0u;
        }
    }
    __builtin_amdgcn_sched_barrier(0);
    __syncthreads();

    // ---- per-wave 512-sample chunk: 15 x (ds_read_b128 A + 4x ds_read_b32 B + MFMA) ----
    // A_m[r][k=(dt,i)] = P[cb + 16r + 8m + dt, i]; lane (r,h) reads one aligned uint4.
    // B_m fragment elems {2d,2d+1} = Bt[bbase + 16m + 2d], bbase = ((4h - cs + 15)<<1)|o.
    const int cb    = wid * 512;
    const int bbase = ((4 * h - cs + 15) << 1) | o;
    float16 acc = {};
    uint4 areg[4];                    // 4-deep A prefetch pipe (static idx post-unroll)
    #pragma unroll
    for (int m = 0; m < 4; ++m)
        areg[m] = *reinterpret_cast<const uint4*>(&Pl[swz(cb + 16 * r + 8 * m + 4 * h)]);
    #pragma unroll
    for (int m = 0; m < NM; ++m) {
        uint4 bq;
        bq.x = Bt[bbase + 16 * m + 0];
        bq.y = Bt[bbase + 16 * m + 2];
        bq.z = Bt[bbase + 16 * m + 4];
        bq.w = Bt[bbase + 16 * m + 6];
        acc = __builtin_amdgcn_mfma_f32_32x32x16_bf16(
                  __builtin_bit_cast(short8, areg[m & 3]),
                  __builtin_bit_cast(short8, bq), acc, 0, 0, 0);
        if (m + 4 < NM)
            areg[m & 3] = *reinterpret_cast<const uint4*>(
                              &Pl[swz(cb + 16 * r + 8 * (m + 4) + 4 * h)]);
    }

    // ---- epilogue: straight from accumulators, no LDS round-trip ----
    // C/D: col = lane&31, row = (reg&3) + 8*(reg>>2) + 4*(lane>>5);
    // out-word index = base*2 + 32*row + colc -> per j the wave touches two full
    // 128B segments (h=0 rows r, h=1 rows r+4): fully coalesced dwords.
    const float bo   = o ? b[1] : b[0];
    const float coef = 0.066268f * exp10f(power[0] * 0.1f);
    #pragma unroll
    for (int j = 0; j < 16; ++j) {
        const int row = (j & 3) + 8 * (j >> 2) + 4 * h;
        const int n   = tile_start + cb + 16 * row + cs;
        if (n < NVALID) {
            const float Ax = xa[(n + N0) * 2 + o];
            const float Bx = xb[(n + N0) * 2 + o];
            float sn, cn;
            __sincosf((acc[j] + bo) * coef, &sn, &cn);
            const unsigned ov = pk(Bx * cn - Ax * sn, Ax * cn + Bx * sn);
            __builtin_nontemporal_store(ov, &out[n * 2 + o]);   // out never re-read
        }
    }
}

extern "C" void kernel_launch(void* const* d_in, const int* in_sizes, int n_in,
                              void* d_out, int out_size, void* d_ws, size_t ws_size,
                              hipStream_t stream) {
    // Bind by size (robust): big arrays = x streams, 404 = W, 2 = b, 1 = power.
    const float* big[2] = {nullptr, nullptr};
    const float* W = nullptr; const float* b = nullptr; const float* power = nullptr;
    int nbig = 0;
    for (int i = 0; i < n_in; ++i) {
        const float* p = (const float*)d_in[i];
        const int sz = in_sizes[i];
        if (sz == NFFT * NMODES)       { if (nbig < 2) big[nbig++] = p; }
        else if (sz == NTAPS * NMODES * NMODES) { W = p; }
        else if (sz == NMODES)         { b = p; }
        else if (sz == 1)              { power = p; }
    }

    unsigned* out = (unsigned*)d_out;
    nl_kernel<<<NT, BLOCK, 0, stream>>>(big[0], big[1], W, b, power, out);
}